// Round 2
// baseline (397.794 us; speedup 1.0000x reference)
//
#include <hip/hip_runtime.h>
#include <hip/hip_bf16.h>
#include <hip/hip_fp16.h>

// ScannedRNN (GRU with resets), T=512 B=256 H=INP=256, MI355X gfx950.
//
// Kernel A (gi_proj): gi[t][gate][hid][b] (f16, ws) = X @ w_ih^T + biases.
// Kernel B (gru_scan): 16 time-chunks x 16 batch-tiles; exact reset-lookback;
//   w_hh resident (r,z gates in VGPR, n gate in LDS); h fp32 in regs;
//   ONE raw s_barrier per step (no vmcnt drain), gi prefetched 1 step ahead.

#define T_LEN 512
#define BATCH 256
#define HID   256

typedef __attribute__((ext_vector_type(8))) short s16x8;          // 8 bf16
typedef __attribute__((ext_vector_type(4))) float fx4;            // 4 f32 acc
typedef __attribute__((ext_vector_type(4))) unsigned short u16x4; // 4 f16

#define MFMA16 __builtin_amdgcn_mfma_f32_16x16x32_bf16
#define GATE_STRIDE 65536u            /* 256*256 halves  */
#define T_STRIDE    196608u           /* 3*256*256 halves */

__device__ __forceinline__ unsigned short f2bf(float f) {
  union { float f; unsigned u; } v; v.f = f;
  unsigned r = v.u + 0x7fffu + ((v.u >> 16) & 1u);   // RNE
  return (unsigned short)(r >> 16);
}

__device__ __forceinline__ s16x8 pack8(float4 a, float4 b) {
  s16x8 f;
  f[0] = (short)f2bf(a.x); f[1] = (short)f2bf(a.y);
  f[2] = (short)f2bf(a.z); f[3] = (short)f2bf(a.w);
  f[4] = (short)f2bf(b.x); f[5] = (short)f2bf(b.y);
  f[6] = (short)f2bf(b.z); f[7] = (short)f2bf(b.w);
  return f;
}

// 768x256 f32 weights -> bf16 MFMA B-fragments. Wave w owns gate cols
// {16w, 256+16w, 512+16w}; r,z -> VGPR wr[2][8]; n -> LDS (128 KiB).
__device__ __forceinline__ void load_weights(const float* __restrict__ W,
                                             s16x8 (&wr)[2][8], char* Wlds,
                                             int tid, int wid, int col, int kgrp) {
#pragma unroll
  for (int n = 0; n < 2; ++n) {
    int g = n * 256 + wid * 16 + col;
#pragma unroll
    for (int s8 = 0; s8 < 8; ++s8) {
      int k = s8 * 32 + kgrp * 8;
      const float4* p = (const float4*)(W + g * 256 + k);
      wr[n][s8] = pack8(p[0], p[1]);
    }
  }
#pragma unroll
  for (int q = 0; q < 8; ++q) {
    int li = tid + q * 1024;            // 8192 fragment lines of 16B
    int wv = li >> 9, s8 = (li >> 6) & 7, l = li & 63;
    int g = 512 + wv * 16 + (l & 15);
    int k = s8 * 32 + (l >> 4) * 8;
    const float4* p = (const float4*)(W + g * 256 + k);
    *(s16x8*)(Wlds + li * 16) = pack8(p[0], p[1]);
  }
}

__device__ __forceinline__ void soft_barrier() {
  asm volatile("s_waitcnt lgkmcnt(0)" ::: "memory");
  __builtin_amdgcn_s_barrier();
  __builtin_amdgcn_sched_barrier(0);
  asm volatile("" ::: "memory");
}

// ---------------- Kernel A: input projection -> gi (f16) ----------------
__global__ __launch_bounds__(1024) void gi_proj_kernel(
    const float* __restrict__ X, const float* __restrict__ w_ih,
    const float* __restrict__ b_ih, const float* __restrict__ b_hh,
    __half* __restrict__ gi) {
  __shared__ __align__(16) char Wlds[131072];
  __shared__ __align__(16) char Ald[2][8192];   // 16x256 bf16, swizzled, dbuf

  const int tid = threadIdx.x;
  const int wid = tid >> 6, lane = tid & 63;
  const int col = lane & 15, kgrp = lane >> 4;

  s16x8 wr[2][8];
  load_weights(w_ih, wr, Wlds, tid, wid, col, kgrp);

  float bias0, bias1, bias2;
  {
    int gb = wid * 16 + col;
    bias0 = b_ih[gb]       + b_hh[gb];        // fold b_hh for r
    bias1 = b_ih[256 + gb] + b_hh[256 + gb];  // fold b_hh for z
    bias2 = b_ih[512 + gb];                   // n: b_hh applied inside r*( ) in scan
  }

  const int e4 = tid * 4;
  const int srow = e4 >> 8, sk = e4 & 255;
  const unsigned sbyte = ((unsigned)(srow * 512 + sk * 2)) ^ ((unsigned)(srow & 7) << 4);

  float4 xcur = *(const float4*)(X + (size_t)(blockIdx.x * 16 + srow) * 256 + sk);

  int parity = 0;
  for (int chunk = blockIdx.x; chunk < (T_LEN * BATCH) / 16; chunk += 256) {
    char* ab = Ald[parity];
    {
      unsigned lo = (unsigned)f2bf(xcur.x) | ((unsigned)f2bf(xcur.y) << 16);
      unsigned hi = (unsigned)f2bf(xcur.z) | ((unsigned)f2bf(xcur.w) << 16);
      uint2 v; v.x = lo; v.y = hi;
      *(uint2*)(ab + sbyte) = v;
    }
    int nchunk = chunk + 256;
    if (nchunk < (T_LEN * BATCH) / 16)
      xcur = *(const float4*)(X + (size_t)(nchunk * 16 + srow) * 256 + sk);

    soft_barrier();   // stage visible; xcur load + gi stores stay in flight

    fx4 acc0 = {0.f, 0.f, 0.f, 0.f}, acc1 = acc0, acc2 = acc0;
#pragma unroll
    for (int s8 = 0; s8 < 8; ++s8) {
      unsigned aoff = ((unsigned)(col * 512 + (s8 * 32 + kgrp * 8) * 2)) ^
                      ((unsigned)(col & 7) << 4);
      s16x8 af = *(const s16x8*)(ab + aoff);
      s16x8 w2 = *(const s16x8*)(Wlds + ((wid * 8 + s8) * 64 + lane) * 16);
      acc0 = MFMA16(af, wr[0][s8], acc0, 0, 0, 0);
      acc1 = MFMA16(af, wr[1][s8], acc1, 0, 0, 0);
      acc2 = MFMA16(af, w2, acc2, 0, 0, 0);
    }

    // gi[t][gate][hid][b] : one u16x4 per gate (b = btile*16 + kgrp*4 + j)
    int t = chunk >> 4, btile = chunk & 15;
    __half* gb = gi + ((size_t)t * 3 * 256 + wid * 16 + col) * 256 + btile * 16 + kgrp * 4;
    u16x4 o0, o1, o2;
#pragma unroll
    for (int j = 0; j < 4; ++j) {
      o0[j] = __half_as_ushort(__float2half(acc0[j] + bias0));
      o1[j] = __half_as_ushort(__float2half(acc1[j] + bias1));
      o2[j] = __half_as_ushort(__float2half(acc2[j] + bias2));
    }
    *(u16x4*)(gb) = o0;
    *(u16x4*)(gb + GATE_STRIDE) = o1;
    *(u16x4*)(gb + 2 * GATE_STRIDE) = o2;
    parity ^= 1;
  }
}

// ---------------- Kernel B: chunked GRU scan ----------------
__global__ __launch_bounds__(1024) void gru_scan_kernel(
    const float* __restrict__ carry, const __half* __restrict__ gi,
    const int* __restrict__ resets, const float* __restrict__ w_hh,
    const float* __restrict__ b_hh, float* __restrict__ out) {
  __shared__ __align__(16) char Wlds[131072];
  __shared__ __align__(16) char Ald[2][8192];   // h bf16 A-tile, swizzled, dbuf
  __shared__ int lastreset[16];

  const int tid = threadIdx.x;
  const int wid = tid >> 6, lane = tid & 63;
  const int col = lane & 15, kgrp = lane >> 4;
  // XCD-pair swizzle: xcd (bid&7) owns b-tiles {2*xcd, 2*xcd+1} -> gi 64B
  // sectors split across two b-tiles stay in one XCD L2.
  const int bid = blockIdx.x;
  const int bt = ((bid & 7) << 1) | ((bid >> 3) & 1);
  const int c  = bid >> 4;
  const int b0 = bt * 16, t0 = c * 32, t1 = t0 + 32;
  const int hid = wid * 16 + col;

  s16x8 wr[2][8];
  load_weights(w_hh, wr, Wlds, tid, wid, col, kgrp);
  const float bhhn = b_hh[512 + hid];

  // ---- exact scan start: min over batch tile of (last reset < t0) ----
  int s, useCarry;
  if (c == 0) {
    s = 0; useCarry = 1;
  } else {
    if (tid < 16) lastreset[tid] = -1;
    for (int base = t0 - 64;; base -= 64) {
      __syncthreads();
      int tt = base + (tid >> 4);
      if (tt >= 0 && tt < t0) {
        if (resets[tt * BATCH + b0 + (tid & 15)] != 0)
          atomicMax(&lastreset[tid & 15], tt);
      }
      __syncthreads();
      int mn = t0, all = 1;
#pragma unroll
      for (int i = 0; i < 16; ++i) {
        int v = lastreset[i];
        all &= (v >= 0) ? 1 : 0;
        mn = min(mn, v < 0 ? t0 : v);
      }
      if (all) { s = mn; useCarry = 0; break; }
      if (base <= 0) { s = 0; useCarry = 1; break; }
    }
  }

  // ---- init state at t=s (reset[s] pre-applied) into Ald[0] ----
  {
    int e4 = tid * 4, row = e4 >> 8, k = e4 & 255;
    int rst = resets[s * BATCH + b0 + row];
    float4 v = {0.f, 0.f, 0.f, 0.f};
    if (useCarry && !rst) v = *(const float4*)(carry + (size_t)(b0 + row) * HID + k);
    unsigned lo = (unsigned)f2bf(v.x) | ((unsigned)f2bf(v.y) << 16);
    unsigned hi = (unsigned)f2bf(v.z) | ((unsigned)f2bf(v.w) << 16);
    unsigned byteoff = ((unsigned)(row * 512 + k * 2)) ^ ((unsigned)(row & 7) << 4);
    uint2 u; u.x = lo; u.y = hi;
    *(uint2*)(Ald[0] + byteoff) = u;
  }
  float hprev[4];
#pragma unroll
  for (int j = 0; j < 4; ++j) {
    int b = kgrp * 4 + j;
    int rst = resets[s * BATCH + b0 + b];
    float hv = 0.f;
    if (useCarry && !rst) hv = carry[(size_t)(b0 + b) * HID + hid];
    hprev[j] = hv;
  }
  __syncthreads();

  // ---- software-pipelined scan: gi/resets prefetched one step ahead ----
  const __half* gp = gi + ((size_t)s * 3 * 256 + hid) * 256 + b0 + kgrp * 4;
  float* op = out + 65536 + ((size_t)s * BATCH + b0 + kgrp * 4) * HID + hid;
  const int* rbase = resets + b0 + kgrp * 4;

  u16x4 gC0 = *(const u16x4*)(gp);
  u16x4 gC1 = *(const u16x4*)(gp + GATE_STRIDE);
  u16x4 gC2 = *(const u16x4*)(gp + 2 * GATE_STRIDE);
  int4  rnC = *(const int4*)(rbase + (size_t)min(s + 1, T_LEN - 1) * BATCH);

  for (int t = s; t < t1; ++t) {
    // prefetch t+1 (clamped re-read on last iter; values unused)
    const bool more = (t + 1 < t1);
    const __half* gq = gp + (more ? T_STRIDE : 0u);
    u16x4 gN0 = *(const u16x4*)(gq);
    u16x4 gN1 = *(const u16x4*)(gq + GATE_STRIDE);
    u16x4 gN2 = *(const u16x4*)(gq + 2 * GATE_STRIDE);
    int4  rnN = *(const int4*)(rbase + (size_t)min(t + 2, T_LEN - 1) * BATCH);

    const char* ab = Ald[(t - s) & 1];
    fx4 acc0 = {0.f, 0.f, 0.f, 0.f}, acc1 = acc0, acc2 = acc0;
#pragma unroll
    for (int s8 = 0; s8 < 8; ++s8) {
      unsigned aoff = ((unsigned)(col * 512 + (s8 * 32 + kgrp * 8) * 2)) ^
                      ((unsigned)(col & 7) << 4);
      s16x8 af = *(const s16x8*)(ab + aoff);
      s16x8 w2 = *(const s16x8*)(Wlds + ((wid * 8 + s8) * 64 + lane) * 16);
      acc0 = MFMA16(af, wr[0][s8], acc0, 0, 0, 0);
      acc1 = MFMA16(af, wr[1][s8], acc1, 0, 0, 0);
      acc2 = MFMA16(af, w2, acc2, 0, 0, 0);
    }

    char* aw = (char*)Ald[((t - s) & 1) ^ 1];
    const bool wr_out = (t >= t0);
    const bool lastT  = (t + 1 >= T_LEN);
#pragma unroll
    for (int j = 0; j < 4; ++j) {
      int b = kgrp * 4 + j;
      float pr = __half2float(__ushort_as_half(gC0[j])) + acc0[j];
      float pz = __half2float(__ushort_as_half(gC1[j])) + acc1[j];
      float r = __builtin_amdgcn_rcpf(1.f + __expf(-pr));
      float z = __builtin_amdgcn_rcpf(1.f + __expf(-pz));
      float pn = __half2float(__ushort_as_half(gC2[j])) + r * (acc2[j] + bhhn);
      float n = 1.f - 2.f * __builtin_amdgcn_rcpf(1.f + __expf(2.f * pn));
      float hnew = (1.f - z) * n + z * hprev[j];
      if (wr_out) op[j * HID] = hnew;
      int rj = (j == 0) ? rnC.x : (j == 1) ? rnC.y : (j == 2) ? rnC.z : rnC.w;
      if (lastT) rj = 0;
      float hk = rj ? 0.f : hnew;                       // pre-apply reset[t+1]
      hprev[j] = hk;
      unsigned hoff = ((unsigned)(b * 512 + hid * 2)) ^ ((unsigned)(b & 7) << 4);
      *(unsigned short*)(aw + hoff) = f2bf(hk);
    }

    gC0 = gN0; gC1 = gN1; gC2 = gN2; rnC = rnN;
    gp = gq;
    op += 65536;
    soft_barrier();   // lgkm drain only: gi prefetch + out stores stay in flight
  }

  if (c == 15) {       // h_final = h after t=511 (reset guarded off)
#pragma unroll
    for (int j = 0; j < 4; ++j)
      out[(size_t)(b0 + kgrp * 4 + j) * HID + hid] = hprev[j];
  }
}

extern "C" void kernel_launch(void* const* d_in, const int* in_sizes, int n_in,
                              void* d_out, int out_size, void* d_ws, size_t ws_size,
                              hipStream_t stream) {
  const float* carry = (const float*)d_in[0];
  const float* X     = (const float*)d_in[1];
  const int*   rsts  = (const int*)d_in[2];
  const float* w_ih  = (const float*)d_in[3];
  const float* w_hh  = (const float*)d_in[4];
  const float* b_ih  = (const float*)d_in[5];
  const float* b_hh  = (const float*)d_in[6];
  float* out = (float*)d_out;

  const size_t gi_bytes = (size_t)T_LEN * BATCH * 3 * HID * sizeof(__half);  // 192 MiB
  if (ws_size < gi_bytes) return;
  __half* gi = (__half*)d_ws;

  gi_proj_kernel<<<256, 1024, 0, stream>>>(X, w_ih, b_ih, b_hh, gi);
  gru_scan_kernel<<<256, 1024, 0, stream>>>(carry, gi, rsts, w_hh, b_hh, out);
}

// Round 3
// 324.225 us; speedup vs baseline: 1.2269x; 1.2269x over previous
//
#include <hip/hip_runtime.h>
#include <hip/hip_bf16.h>
#include <hip/hip_fp16.h>

// ScannedRNN (GRU with resets), T=512 B=256 H=INP=256, MI355X gfx950.
//
// gi layout (f16, in d_ws): gi[t][btile][gate][hid][bsub]
//   -> each (t,btile) is a contiguous 24 KiB block, private to ONE scan WG.
//   Proj writes it fully coalesced (512 B/wave/gate); scan reads 3 x u16x4
//   per thread per step (fully coalesced, 4 cache lines per instr).
//
// Kernel A (gi_proj): gi = X @ w_ih^T + b_ih (+ b_hh folded for r,z).
// Kernel B (gru_scan): 16 time-chunks x 16 batch-tiles; exact reset-lookback;
//   w_hh resident (r,z in VGPR/AGPR, n in LDS); h fp32 in regs; ONE raw
//   s_barrier per step (lgkm drain only, vmcnt never drained), gi prefetched
//   one step ahead.

#define T_LEN 512
#define BATCH 256
#define HID   256

typedef __attribute__((ext_vector_type(8))) short s16x8;          // 8 bf16
typedef __attribute__((ext_vector_type(4))) float fx4;            // 4 f32 acc
typedef __attribute__((ext_vector_type(4))) unsigned short u16x4; // 4 f16

#define MFMA16 __builtin_amdgcn_mfma_f32_16x16x32_bf16

// gi strides in halves: [t][btile][gate][hid][bsub]
#define GATE_STRIDE 4096u              /* 256 hid * 16 bsub */
#define BLK_STRIDE  12288u             /* 3 gates */
#define T_STRIDE    196608u            /* 16 btiles */

__device__ __forceinline__ unsigned short f2bf(float f) {
  union { float f; unsigned u; } v; v.f = f;
  unsigned r = v.u + 0x7fffu + ((v.u >> 16) & 1u);   // RNE
  return (unsigned short)(r >> 16);
}

__device__ __forceinline__ s16x8 pack8(float4 a, float4 b) {
  s16x8 f;
  f[0] = (short)f2bf(a.x); f[1] = (short)f2bf(a.y);
  f[2] = (short)f2bf(a.z); f[3] = (short)f2bf(a.w);
  f[4] = (short)f2bf(b.x); f[5] = (short)f2bf(b.y);
  f[6] = (short)f2bf(b.z); f[7] = (short)f2bf(b.w);
  return f;
}

// 768x256 f32 weights -> bf16 MFMA B-fragments. Wave w owns gate cols
// {16w, 256+16w, 512+16w}; r,z -> VGPR wr[2][8]; n -> LDS (128 KiB).
__device__ __forceinline__ void load_weights(const float* __restrict__ W,
                                             s16x8 (&wr)[2][8], char* Wlds,
                                             int tid, int wid, int col, int kgrp) {
#pragma unroll
  for (int n = 0; n < 2; ++n) {
    int g = n * 256 + wid * 16 + col;
#pragma unroll
    for (int s8 = 0; s8 < 8; ++s8) {
      int k = s8 * 32 + kgrp * 8;
      const float4* p = (const float4*)(W + g * 256 + k);
      wr[n][s8] = pack8(p[0], p[1]);
    }
  }
#pragma unroll
  for (int q = 0; q < 8; ++q) {
    int li = tid + q * 1024;            // 8192 fragment lines of 16B
    int wv = li >> 9, s8 = (li >> 6) & 7, l = li & 63;
    int g = 512 + wv * 16 + (l & 15);
    int k = s8 * 32 + (l >> 4) * 8;
    const float4* p = (const float4*)(W + g * 256 + k);
    *(s16x8*)(Wlds + li * 16) = pack8(p[0], p[1]);
  }
}

__device__ __forceinline__ void soft_barrier() {
  asm volatile("s_waitcnt lgkmcnt(0)" ::: "memory");
  __builtin_amdgcn_s_barrier();
  __builtin_amdgcn_sched_barrier(0);
  asm volatile("" ::: "memory");
}

// ---------------- Kernel A: input projection -> gi (f16) ----------------
__global__ __launch_bounds__(1024) void gi_proj_kernel(
    const float* __restrict__ X, const float* __restrict__ w_ih,
    const float* __restrict__ b_ih, const float* __restrict__ b_hh,
    __half* __restrict__ gi) {
  __shared__ __align__(16) char Wlds[131072];
  __shared__ __align__(16) char Ald[2][8192];   // 16x256 bf16, swizzled, dbuf

  const int tid = threadIdx.x;
  const int wid = tid >> 6, lane = tid & 63;
  const int col = lane & 15, kgrp = lane >> 4;

  s16x8 wr[2][8];
  load_weights(w_ih, wr, Wlds, tid, wid, col, kgrp);

  float bias0, bias1, bias2;
  {
    int gb = wid * 16 + col;
    bias0 = b_ih[gb]       + b_hh[gb];        // fold b_hh for r
    bias1 = b_ih[256 + gb] + b_hh[256 + gb];  // fold b_hh for z
    bias2 = b_ih[512 + gb];                   // n: b_hh applied inside r*( ) in scan
  }

  const int e4 = tid * 4;
  const int srow = e4 >> 8, sk = e4 & 255;
  const unsigned sbyte = ((unsigned)(srow * 512 + sk * 2)) ^ ((unsigned)(srow & 7) << 4);

  // chunk = t*16 + btile ; X rows = chunk*16 + r = t*256 + btile*16 + r
  float4 xcur = *(const float4*)(X + (size_t)(blockIdx.x * 16 + srow) * 256 + sk);

  int parity = 0;
  for (int chunk = blockIdx.x; chunk < (T_LEN * BATCH) / 16; chunk += 256) {
    char* ab = Ald[parity];
    {
      unsigned lo = (unsigned)f2bf(xcur.x) | ((unsigned)f2bf(xcur.y) << 16);
      unsigned hi = (unsigned)f2bf(xcur.z) | ((unsigned)f2bf(xcur.w) << 16);
      uint2 v; v.x = lo; v.y = hi;
      *(uint2*)(ab + sbyte) = v;
    }
    int nchunk = chunk + 256;
    if (nchunk < (T_LEN * BATCH) / 16)
      xcur = *(const float4*)(X + (size_t)(nchunk * 16 + srow) * 256 + sk);

    soft_barrier();   // stage visible; xcur load + gi stores stay in flight

    fx4 acc0 = {0.f, 0.f, 0.f, 0.f}, acc1 = acc0, acc2 = acc0;
#pragma unroll
    for (int s8 = 0; s8 < 8; ++s8) {
      unsigned aoff = ((unsigned)(col * 512 + (s8 * 32 + kgrp * 8) * 2)) ^
                      ((unsigned)(col & 7) << 4);
      s16x8 af = *(const s16x8*)(ab + aoff);
      s16x8 w2 = *(const s16x8*)(Wlds + ((wid * 8 + s8) * 64 + lane) * 16);
      acc0 = MFMA16(af, wr[0][s8], acc0, 0, 0, 0);
      acc1 = MFMA16(af, wr[1][s8], acc1, 0, 0, 0);
      acc2 = MFMA16(af, w2, acc2, 0, 0, 0);
    }

    // store: (t,btile) block, lane -> (gate, hid=wid*16+col, bsub=kgrp*4+j)
    __half* gb = gi + (size_t)chunk * BLK_STRIDE +
                 (unsigned)(wid * 16 + col) * 16 + kgrp * 4;
    u16x4 o0, o1, o2;
#pragma unroll
    for (int j = 0; j < 4; ++j) {
      o0[j] = __half_as_ushort(__float2half(acc0[j] + bias0));
      o1[j] = __half_as_ushort(__float2half(acc1[j] + bias1));
      o2[j] = __half_as_ushort(__float2half(acc2[j] + bias2));
    }
    *(u16x4*)(gb) = o0;
    *(u16x4*)(gb + GATE_STRIDE) = o1;
    *(u16x4*)(gb + 2 * GATE_STRIDE) = o2;
    parity ^= 1;
  }
}

// ---------------- Kernel B: chunked GRU scan ----------------
__global__ __launch_bounds__(1024) void gru_scan_kernel(
    const float* __restrict__ carry, const __half* __restrict__ gi,
    const int* __restrict__ resets, const float* __restrict__ w_hh,
    const float* __restrict__ b_hh, float* __restrict__ out) {
  __shared__ __align__(16) char Wlds[131072];
  __shared__ __align__(16) char Ald[2][8192];   // h bf16 A-tile, swizzled, dbuf
  __shared__ int lastreset[16];

  const int tid = threadIdx.x;
  const int wid = tid >> 6, lane = tid & 63;
  const int col = lane & 15, kgrp = lane >> 4;
  const int bid = blockIdx.x;
  const int bt = bid & 15, c = bid >> 4;   // gi blocks are WG-private: no swizzle
  const int b0 = bt * 16, t0 = c * 32, t1 = t0 + 32;
  const int hid = wid * 16 + col;

  s16x8 wr[2][8];
  load_weights(w_hh, wr, Wlds, tid, wid, col, kgrp);
  const float bhhn = b_hh[512 + hid];

  // ---- exact scan start: min over batch tile of (last reset < t0) ----
  int s, useCarry;
  if (c == 0) {
    s = 0; useCarry = 1;
  } else {
    if (tid < 16) lastreset[tid] = -1;
    for (int base = t0 - 64;; base -= 64) {
      __syncthreads();
      int tt = base + (tid >> 4);
      if (tt >= 0 && tt < t0) {
        if (resets[tt * BATCH + b0 + (tid & 15)] != 0)
          atomicMax(&lastreset[tid & 15], tt);
      }
      __syncthreads();
      int mn = t0, all = 1;
#pragma unroll
      for (int i = 0; i < 16; ++i) {
        int v = lastreset[i];
        all &= (v >= 0) ? 1 : 0;
        mn = min(mn, v < 0 ? t0 : v);
      }
      if (all) { s = mn; useCarry = 0; break; }
      if (base <= 0) { s = 0; useCarry = 1; break; }
    }
  }

  // ---- init state at t=s (reset[s] pre-applied) into Ald[0] ----
  {
    int e4 = tid * 4, row = e4 >> 8, k = e4 & 255;
    int rst = resets[s * BATCH + b0 + row];
    float4 v = {0.f, 0.f, 0.f, 0.f};
    if (useCarry && !rst) v = *(const float4*)(carry + (size_t)(b0 + row) * HID + k);
    unsigned lo = (unsigned)f2bf(v.x) | ((unsigned)f2bf(v.y) << 16);
    unsigned hi = (unsigned)f2bf(v.z) | ((unsigned)f2bf(v.w) << 16);
    unsigned byteoff = ((unsigned)(row * 512 + k * 2)) ^ ((unsigned)(row & 7) << 4);
    uint2 u; u.x = lo; u.y = hi;
    *(uint2*)(Ald[0] + byteoff) = u;
  }
  float hprev[4];
#pragma unroll
  for (int j = 0; j < 4; ++j) {
    int b = kgrp * 4 + j;
    int rst = resets[s * BATCH + b0 + b];
    float hv = 0.f;
    if (useCarry && !rst) hv = carry[(size_t)(b0 + b) * HID + hid];
    hprev[j] = hv;
  }
  __syncthreads();

  // ---- software-pipelined scan: gi/resets prefetched one step ahead ----
  const __half* gp = gi + (size_t)(s * 16 + bt) * BLK_STRIDE + (unsigned)hid * 16 + kgrp * 4;
  float* op = out + 65536 + ((size_t)s * BATCH + b0 + kgrp * 4) * HID + hid;
  const int* rbase = resets + b0 + kgrp * 4;

  u16x4 gC0 = *(const u16x4*)(gp);
  u16x4 gC1 = *(const u16x4*)(gp + GATE_STRIDE);
  u16x4 gC2 = *(const u16x4*)(gp + 2 * GATE_STRIDE);
  int4  rnC = *(const int4*)(rbase + (size_t)min(s + 1, T_LEN - 1) * BATCH);

  for (int t = s; t < t1; ++t) {
    // prefetch t+1 (clamped re-read on last iter; values unused)
    const bool more = (t + 1 < t1);
    const __half* gq = gp + (more ? T_STRIDE : 0u);
    u16x4 gN0 = *(const u16x4*)(gq);
    u16x4 gN1 = *(const u16x4*)(gq + GATE_STRIDE);
    u16x4 gN2 = *(const u16x4*)(gq + 2 * GATE_STRIDE);
    int4  rnN = *(const int4*)(rbase + (size_t)min(t + 2, T_LEN - 1) * BATCH);

    const char* ab = Ald[(t - s) & 1];
    fx4 acc0 = {0.f, 0.f, 0.f, 0.f}, acc1 = acc0, acc2 = acc0;
#pragma unroll
    for (int s8 = 0; s8 < 8; ++s8) {
      unsigned aoff = ((unsigned)(col * 512 + (s8 * 32 + kgrp * 8) * 2)) ^
                      ((unsigned)(col & 7) << 4);
      s16x8 af = *(const s16x8*)(ab + aoff);
      s16x8 w2 = *(const s16x8*)(Wlds + ((wid * 8 + s8) * 64 + lane) * 16);
      acc0 = MFMA16(af, wr[0][s8], acc0, 0, 0, 0);
      acc1 = MFMA16(af, wr[1][s8], acc1, 0, 0, 0);
      acc2 = MFMA16(af, w2, acc2, 0, 0, 0);
    }

    char* aw = (char*)Ald[((t - s) & 1) ^ 1];
    const bool wr_out = (t >= t0);
    const bool lastT  = (t + 1 >= T_LEN);
#pragma unroll
    for (int j = 0; j < 4; ++j) {
      int b = kgrp * 4 + j;
      float pr = __half2float(__ushort_as_half(gC0[j])) + acc0[j];
      float pz = __half2float(__ushort_as_half(gC1[j])) + acc1[j];
      float r = __builtin_amdgcn_rcpf(1.f + __expf(-pr));
      float z = __builtin_amdgcn_rcpf(1.f + __expf(-pz));
      float pn = __half2float(__ushort_as_half(gC2[j])) + r * (acc2[j] + bhhn);
      float n = 1.f - 2.f * __builtin_amdgcn_rcpf(1.f + __expf(2.f * pn));
      float hnew = (1.f - z) * n + z * hprev[j];
      if (wr_out) op[j * HID] = hnew;
      int rj = (j == 0) ? rnC.x : (j == 1) ? rnC.y : (j == 2) ? rnC.z : rnC.w;
      if (lastT) rj = 0;
      float hk = rj ? 0.f : hnew;                       // pre-apply reset[t+1]
      hprev[j] = hk;
      unsigned hoff = ((unsigned)(b * 512 + hid * 2)) ^ ((unsigned)(b & 7) << 4);
      *(unsigned short*)(aw + hoff) = f2bf(hk);
    }

    gC0 = gN0; gC1 = gN1; gC2 = gN2; rnC = rnN;
    gp = gq;
    op += 65536;
    soft_barrier();   // lgkm drain only: gi prefetch + out stores stay in flight
  }

  if (c == 15) {       // h_final = h after t=511 (reset guarded off)
#pragma unroll
    for (int j = 0; j < 4; ++j)
      out[(size_t)(b0 + kgrp * 4 + j) * HID + hid] = hprev[j];
  }
}

extern "C" void kernel_launch(void* const* d_in, const int* in_sizes, int n_in,
                              void* d_out, int out_size, void* d_ws, size_t ws_size,
                              hipStream_t stream) {
  const float* carry = (const float*)d_in[0];
  const float* X     = (const float*)d_in[1];
  const int*   rsts  = (const int*)d_in[2];
  const float* w_ih  = (const float*)d_in[3];
  const float* w_hh  = (const float*)d_in[4];
  const float* b_ih  = (const float*)d_in[5];
  const float* b_hh  = (const float*)d_in[6];
  float* out = (float*)d_out;

  const size_t gi_bytes = (size_t)T_LEN * BATCH * 3 * HID * sizeof(__half);  // 192 MiB
  if (ws_size < gi_bytes) return;
  __half* gi = (__half*)d_ws;

  gi_proj_kernel<<<256, 1024, 0, stream>>>(X, w_ih, b_ih, b_hh, gi);
  gru_scan_kernel<<<256, 1024, 0, stream>>>(carry, gi, rsts, w_hh, b_hh, out);
}

// Round 4
// 246.279 us; speedup vs baseline: 1.6152x; 1.3165x over previous
//
#include <hip/hip_runtime.h>
#include <hip/hip_bf16.h>
#include <hip/hip_fp16.h>

// ScannedRNN (GRU with resets), T=512 B=256 H=INP=256, MI355X gfx950.
//
// Round 4: fix register thrash. 512-thread WGs (8 waves, 2/SIMD) with
// __launch_bounds__(512,2) -> 256 unified regs/wave. Each wave owns TWO
// hid-tiles; r,z weights (128 VGPR) stay in arch registers, n-gate weights
// in LDS (128 KiB). Everything else (gi[t][btile][gate][hid][bsub] blocked
// layout, one lgkm-only barrier/step, 1-step gi prefetch, exact reset
// lookback) unchanged from round 3.

#define T_LEN 512
#define BATCH 256
#define HID   256

typedef __attribute__((ext_vector_type(8))) short s16x8;          // 8 bf16
typedef __attribute__((ext_vector_type(4))) float fx4;            // 4 f32 acc
typedef __attribute__((ext_vector_type(4))) unsigned short u16x4; // 4 f16

#define MFMA16 __builtin_amdgcn_mfma_f32_16x16x32_bf16

// gi strides in halves: [t][btile][gate][hid][bsub]
#define GATE_STRIDE 4096u              /* 256 hid * 16 bsub */
#define BLK_STRIDE  12288u             /* 3 gates */
#define T_STRIDE    196608u            /* 16 btiles */

__device__ __forceinline__ unsigned short f2bf(float f) {
  union { float f; unsigned u; } v; v.f = f;
  unsigned r = v.u + 0x7fffu + ((v.u >> 16) & 1u);   // RNE
  return (unsigned short)(r >> 16);
}

__device__ __forceinline__ s16x8 pack8(float4 a, float4 b) {
  s16x8 f;
  f[0] = (short)f2bf(a.x); f[1] = (short)f2bf(a.y);
  f[2] = (short)f2bf(a.z); f[3] = (short)f2bf(a.w);
  f[4] = (short)f2bf(b.x); f[5] = (short)f2bf(b.y);
  f[6] = (short)f2bf(b.z); f[7] = (short)f2bf(b.w);
  return f;
}

// 768x256 f32 weights -> bf16 MFMA B-fragments. Wave w owns hid-tiles
// {2w, 2w+1}; gate cols {ht*16.., 256+.., 512+..}. r,z -> VGPR wr[2][2][8]
// (128 regs); n -> LDS (128 KiB), 16 hid-tiles x 8 s8 x 64 lanes x 16 B.
__device__ __forceinline__ void load_weights(const float* __restrict__ W,
                                             s16x8 (&wr)[2][2][8], char* Wlds,
                                             int tid, int wid, int col, int kgrp) {
#pragma unroll
  for (int n = 0; n < 2; ++n)
#pragma unroll
    for (int ht = 0; ht < 2; ++ht) {
      int g = n * 256 + (wid * 2 + ht) * 16 + col;
#pragma unroll
      for (int s8 = 0; s8 < 8; ++s8) {
        int k = s8 * 32 + kgrp * 8;
        const float4* p = (const float4*)(W + g * 256 + k);
        wr[n][ht][s8] = pack8(p[0], p[1]);
      }
    }
#pragma unroll
  for (int q = 0; q < 16; ++q) {
    int li = tid + q * 512;             // 8192 fragment lines of 16B
    int wv = li >> 9, s8 = (li >> 6) & 7, l = li & 63;
    int g = 512 + wv * 16 + (l & 15);
    int k = s8 * 32 + (l >> 4) * 8;
    const float4* p = (const float4*)(W + g * 256 + k);
    *(s16x8*)(Wlds + li * 16) = pack8(p[0], p[1]);
  }
}

__device__ __forceinline__ void soft_barrier() {
  asm volatile("s_waitcnt lgkmcnt(0)" ::: "memory");
  __builtin_amdgcn_s_barrier();
  __builtin_amdgcn_sched_barrier(0);
  asm volatile("" ::: "memory");
}

// ---------------- Kernel A: input projection -> gi (f16) ----------------
__global__ __launch_bounds__(512, 2) void gi_proj_kernel(
    const float* __restrict__ X, const float* __restrict__ w_ih,
    const float* __restrict__ b_ih, const float* __restrict__ b_hh,
    __half* __restrict__ gi) {
  __shared__ __align__(16) char Wlds[131072];
  __shared__ __align__(16) char Ald[2][8192];   // 16x256 bf16, swizzled, dbuf

  const int tid = threadIdx.x;
  const int wid = tid >> 6, lane = tid & 63;
  const int col = lane & 15, kgrp = lane >> 4;

  s16x8 wr[2][2][8];
  load_weights(w_ih, wr, Wlds, tid, wid, col, kgrp);

  float bias[2][3];
#pragma unroll
  for (int ht = 0; ht < 2; ++ht) {
    int gb = (wid * 2 + ht) * 16 + col;
    bias[ht][0] = b_ih[gb]       + b_hh[gb];        // fold b_hh for r
    bias[ht][1] = b_ih[256 + gb] + b_hh[256 + gb];  // fold b_hh for z
    bias[ht][2] = b_ih[512 + gb];                   // n: b_hh inside r*( ) in scan
  }

  const int srow = tid >> 5, sk = (tid & 31) * 8;   // 512 thr x 8 f32 = 16x256
  const unsigned sbyte = ((unsigned)(srow * 512 + sk * 2)) ^ ((unsigned)(srow & 7) << 4);

  float4 xc0 = *(const float4*)(X + (size_t)(blockIdx.x * 16 + srow) * 256 + sk);
  float4 xc1 = *(const float4*)(X + (size_t)(blockIdx.x * 16 + srow) * 256 + sk + 4);

  int parity = 0;
  for (int chunk = blockIdx.x; chunk < (T_LEN * BATCH) / 16; chunk += 256) {
    char* ab = Ald[parity];
    {
      uint4 v;
      v.x = (unsigned)f2bf(xc0.x) | ((unsigned)f2bf(xc0.y) << 16);
      v.y = (unsigned)f2bf(xc0.z) | ((unsigned)f2bf(xc0.w) << 16);
      v.z = (unsigned)f2bf(xc1.x) | ((unsigned)f2bf(xc1.y) << 16);
      v.w = (unsigned)f2bf(xc1.z) | ((unsigned)f2bf(xc1.w) << 16);
      *(uint4*)(ab + sbyte) = v;
    }
    int nchunk = chunk + 256;
    if (nchunk < (T_LEN * BATCH) / 16) {
      xc0 = *(const float4*)(X + (size_t)(nchunk * 16 + srow) * 256 + sk);
      xc1 = *(const float4*)(X + (size_t)(nchunk * 16 + srow) * 256 + sk + 4);
    }
    soft_barrier();   // stage visible; X prefetch + gi stores stay in flight

    fx4 acc[2][3];
#pragma unroll
    for (int ht = 0; ht < 2; ++ht)
#pragma unroll
      for (int g = 0; g < 3; ++g)
        acc[ht][g] = (fx4){0.f, 0.f, 0.f, 0.f};

#pragma unroll
    for (int s8 = 0; s8 < 8; ++s8) {
      unsigned aoff = ((unsigned)(col * 512 + (s8 * 32 + kgrp * 8) * 2)) ^
                      ((unsigned)(col & 7) << 4);
      s16x8 af = *(const s16x8*)(ab + aoff);
#pragma unroll
      for (int ht = 0; ht < 2; ++ht) {
        s16x8 w2 = *(const s16x8*)(Wlds + (((wid * 2 + ht) * 8 + s8) * 64 + lane) * 16);
        acc[ht][0] = MFMA16(af, wr[0][ht][s8], acc[ht][0], 0, 0, 0);
        acc[ht][1] = MFMA16(af, wr[1][ht][s8], acc[ht][1], 0, 0, 0);
        acc[ht][2] = MFMA16(af, w2, acc[ht][2], 0, 0, 0);
      }
    }

    // store: (t,btile) block, thread -> (gate, hid, bsub=kgrp*4+j)
#pragma unroll
    for (int ht = 0; ht < 2; ++ht) {
      __half* gb = gi + (size_t)chunk * BLK_STRIDE +
                   (unsigned)((wid * 2 + ht) * 16 + col) * 16 + kgrp * 4;
      u16x4 o0, o1, o2;
#pragma unroll
      for (int j = 0; j < 4; ++j) {
        o0[j] = __half_as_ushort(__float2half(acc[ht][0][j] + bias[ht][0]));
        o1[j] = __half_as_ushort(__float2half(acc[ht][1][j] + bias[ht][1]));
        o2[j] = __half_as_ushort(__float2half(acc[ht][2][j] + bias[ht][2]));
      }
      *(u16x4*)(gb) = o0;
      *(u16x4*)(gb + GATE_STRIDE) = o1;
      *(u16x4*)(gb + 2 * GATE_STRIDE) = o2;
    }
    parity ^= 1;
  }
}

// ---------------- Kernel B: chunked GRU scan ----------------
__global__ __launch_bounds__(512, 2) void gru_scan_kernel(
    const float* __restrict__ carry, const __half* __restrict__ gi,
    const int* __restrict__ resets, const float* __restrict__ w_hh,
    const float* __restrict__ b_hh, float* __restrict__ out) {
  __shared__ __align__(16) char Wlds[131072];
  __shared__ __align__(16) char Ald[2][8192];   // h bf16 A-tile, swizzled, dbuf
  __shared__ int lastreset[16];

  const int tid = threadIdx.x;
  const int wid = tid >> 6, lane = tid & 63;
  const int col = lane & 15, kgrp = lane >> 4;
  const int bid = blockIdx.x;
  const int bt = bid & 15, c = bid >> 4;
  const int b0 = bt * 16, t0 = c * 32, t1 = t0 + 32;
  const int hid0 = wid * 32 + col;              // wave owns hid0, hid0+16

  s16x8 wr[2][2][8];
  load_weights(w_hh, wr, Wlds, tid, wid, col, kgrp);
  const float bhhn0 = b_hh[512 + hid0], bhhn1 = b_hh[512 + hid0 + 16];

  // ---- exact scan start: min over batch tile of (last reset < t0) ----
  int s, useCarry;
  if (c == 0) {
    s = 0; useCarry = 1;
  } else {
    if (tid < 16) lastreset[tid] = -1;
    for (int base = t0 - 32;; base -= 32) {     // 512 thr: 32 t x 16 b per pass
      __syncthreads();
      int tt = base + (tid >> 4);
      if (tt >= 0 && tt < t0) {
        if (resets[tt * BATCH + b0 + (tid & 15)] != 0)
          atomicMax(&lastreset[tid & 15], tt);
      }
      __syncthreads();
      int mn = t0, all = 1;
#pragma unroll
      for (int i = 0; i < 16; ++i) {
        int v = lastreset[i];
        all &= (v >= 0) ? 1 : 0;
        mn = min(mn, v < 0 ? t0 : v);
      }
      if (all) { s = mn; useCarry = 0; break; }
      if (base <= 0) { s = 0; useCarry = 1; break; }
    }
  }

  // ---- init state at t=s (reset[s] pre-applied) into Ald[0] ----
  {
    int row = tid >> 5, k = (tid & 31) * 8;
    int rst = resets[s * BATCH + b0 + row];
    float4 v0 = {0.f, 0.f, 0.f, 0.f}, v1 = v0;
    if (useCarry && !rst) {
      v0 = *(const float4*)(carry + (size_t)(b0 + row) * HID + k);
      v1 = *(const float4*)(carry + (size_t)(b0 + row) * HID + k + 4);
    }
    uint4 u;
    u.x = (unsigned)f2bf(v0.x) | ((unsigned)f2bf(v0.y) << 16);
    u.y = (unsigned)f2bf(v0.z) | ((unsigned)f2bf(v0.w) << 16);
    u.z = (unsigned)f2bf(v1.x) | ((unsigned)f2bf(v1.y) << 16);
    u.w = (unsigned)f2bf(v1.z) | ((unsigned)f2bf(v1.w) << 16);
    unsigned byteoff = ((unsigned)(row * 512 + k * 2)) ^ ((unsigned)(row & 7) << 4);
    *(uint4*)(Ald[0] + byteoff) = u;
  }
  float hprev[2][4];
#pragma unroll
  for (int ht = 0; ht < 2; ++ht)
#pragma unroll
    for (int j = 0; j < 4; ++j) {
      int b = kgrp * 4 + j;
      int rst = resets[s * BATCH + b0 + b];
      float hv = 0.f;
      if (useCarry && !rst) hv = carry[(size_t)(b0 + b) * HID + hid0 + ht * 16];
      hprev[ht][j] = hv;
    }
  __syncthreads();

  // ---- software-pipelined scan: gi/resets prefetched one step ahead ----
  const __half* gp = gi + (size_t)(s * 16 + bt) * BLK_STRIDE + (unsigned)hid0 * 16 + kgrp * 4;
  float* op = out + 65536 + ((size_t)s * BATCH + b0 + kgrp * 4) * HID + hid0;
  const int* rbase = resets + b0 + kgrp * 4;

  u16x4 gC[2][3];
#pragma unroll
  for (int ht = 0; ht < 2; ++ht)
#pragma unroll
    for (int g = 0; g < 3; ++g)
      gC[ht][g] = *(const u16x4*)(gp + ht * 256u + g * GATE_STRIDE);
  int4 rnC = *(const int4*)(rbase + (size_t)min(s + 1, T_LEN - 1) * BATCH);

  for (int t = s; t < t1; ++t) {
    const bool more = (t + 1 < t1);
    const __half* gq = gp + (more ? T_STRIDE : 0u);
    u16x4 gN[2][3];
#pragma unroll
    for (int ht = 0; ht < 2; ++ht)
#pragma unroll
      for (int g = 0; g < 3; ++g)
        gN[ht][g] = *(const u16x4*)(gq + ht * 256u + g * GATE_STRIDE);
    int4 rnN = *(const int4*)(rbase + (size_t)min(t + 2, T_LEN - 1) * BATCH);

    const char* ab = Ald[(t - s) & 1];
    fx4 acc[2][3];
#pragma unroll
    for (int ht = 0; ht < 2; ++ht)
#pragma unroll
      for (int g = 0; g < 3; ++g)
        acc[ht][g] = (fx4){0.f, 0.f, 0.f, 0.f};

#pragma unroll
    for (int s8 = 0; s8 < 8; ++s8) {
      unsigned aoff = ((unsigned)(col * 512 + (s8 * 32 + kgrp * 8) * 2)) ^
                      ((unsigned)(col & 7) << 4);
      s16x8 af = *(const s16x8*)(ab + aoff);
#pragma unroll
      for (int ht = 0; ht < 2; ++ht) {
        s16x8 w2 = *(const s16x8*)(Wlds + (((wid * 2 + ht) * 8 + s8) * 64 + lane) * 16);
        acc[ht][0] = MFMA16(af, wr[0][ht][s8], acc[ht][0], 0, 0, 0);
        acc[ht][1] = MFMA16(af, wr[1][ht][s8], acc[ht][1], 0, 0, 0);
        acc[ht][2] = MFMA16(af, w2, acc[ht][2], 0, 0, 0);
      }
    }

    char* aw = (char*)Ald[((t - s) & 1) ^ 1];
    const bool wr_out = (t >= t0);
    const bool lastT  = (t + 1 >= T_LEN);
#pragma unroll
    for (int j = 0; j < 4; ++j) {
      int b = kgrp * 4 + j;
      int rj = (j == 0) ? rnC.x : (j == 1) ? rnC.y : (j == 2) ? rnC.z : rnC.w;
      if (lastT) rj = 0;
#pragma unroll
      for (int ht = 0; ht < 2; ++ht) {
        float pr = __half2float(__ushort_as_half(gC[ht][0][j])) + acc[ht][0][j];
        float pz = __half2float(__ushort_as_half(gC[ht][1][j])) + acc[ht][1][j];
        float r = __builtin_amdgcn_rcpf(1.f + __expf(-pr));
        float z = __builtin_amdgcn_rcpf(1.f + __expf(-pz));
        float pn = __half2float(__ushort_as_half(gC[ht][2][j])) +
                   r * (acc[ht][2][j] + (ht ? bhhn1 : bhhn0));
        float n = 1.f - 2.f * __builtin_amdgcn_rcpf(1.f + __expf(2.f * pn));
        float hnew = (1.f - z) * n + z * hprev[ht][j];
        if (wr_out) op[j * HID + ht * 16] = hnew;
        float hk = rj ? 0.f : hnew;                 // pre-apply reset[t+1]
        hprev[ht][j] = hk;
        unsigned hoff = ((unsigned)(b * 512 + (hid0 + ht * 16) * 2)) ^
                        ((unsigned)(b & 7) << 4);
        *(unsigned short*)(aw + hoff) = f2bf(hk);
      }
    }

#pragma unroll
    for (int ht = 0; ht < 2; ++ht)
#pragma unroll
      for (int g = 0; g < 3; ++g)
        gC[ht][g] = gN[ht][g];
    rnC = rnN;
    gp = gq;
    op += 65536;
    soft_barrier();   // lgkm drain only: gi prefetch + out stores stay in flight
  }

  if (c == 15) {       // h_final = h after t=511 (reset guarded off)
#pragma unroll
    for (int ht = 0; ht < 2; ++ht)
#pragma unroll
      for (int j = 0; j < 4; ++j)
        out[(size_t)(b0 + kgrp * 4 + j) * HID + hid0 + ht * 16] = hprev[ht][j];
  }
}

extern "C" void kernel_launch(void* const* d_in, const int* in_sizes, int n_in,
                              void* d_out, int out_size, void* d_ws, size_t ws_size,
                              hipStream_t stream) {
  const float* carry = (const float*)d_in[0];
  const float* X     = (const float*)d_in[1];
  const int*   rsts  = (const int*)d_in[2];
  const float* w_ih  = (const float*)d_in[3];
  const float* w_hh  = (const float*)d_in[4];
  const float* b_ih  = (const float*)d_in[5];
  const float* b_hh  = (const float*)d_in[6];
  float* out = (float*)d_out;

  const size_t gi_bytes = (size_t)T_LEN * BATCH * 3 * HID * sizeof(__half);  // 192 MiB
  if (ws_size < gi_bytes) return;
  __half* gi = (__half*)d_ws;

  gi_proj_kernel<<<256, 512, 0, stream>>>(X, w_ih, b_ih, b_hh, gi);
  gru_scan_kernel<<<256, 512, 0, stream>>>(carry, gi, rsts, w_hh, b_hh, out);
}